// Round 1
// baseline (433.187 us; speedup 1.0000x reference)
//
#include <hip/hip_runtime.h>

#define NB 32  // batch size B (fixed by problem)

// ---------------------------------------------------------------------------
// x (B, N) -> xt (N, B): 32x32 LDS tile transpose, coalesced read and write.
// ---------------------------------------------------------------------------
__global__ void transpose_x_kernel(const float* __restrict__ x,
                                   float* __restrict__ xt, int N) {
    __shared__ float tile[32][33];  // +1 pad: avoid bank conflicts
    int n0 = blockIdx.x * 32;
    // read: lanes (threadIdx.x) sweep n (contiguous), i sweeps batch rows
    for (int i = threadIdx.y; i < 32; i += 8) {
        int n = n0 + threadIdx.x;
        tile[i][threadIdx.x] = (n < N) ? x[(size_t)i * N + n] : 0.f;
    }
    __syncthreads();
    // write: lanes sweep batch (contiguous in xt), i sweeps n
    for (int i = threadIdx.y; i < 32; i += 8) {
        int n = n0 + i;
        if (n < N) xt[(size_t)n * NB + threadIdx.x] = tile[threadIdx.x][i];
    }
}

// ---------------------------------------------------------------------------
// One thread per (edge, batch) pair. Wave64 = 2 edges x 32 batches:
//  - xt gather: 2 contiguous 128B segments (coalesced)
//  - yt atomics: 2 contiguous 128B segments (good L2 atomic locality)
// ---------------------------------------------------------------------------
__global__ void scatter_kernel(const int* __restrict__ src,
                               const int* __restrict__ dst,
                               const float* __restrict__ vals,
                               const float* __restrict__ xt,
                               float* __restrict__ yt, int nnz) {
    long long tid = (long long)blockIdx.x * blockDim.x + threadIdx.x;
    int e = (int)(tid >> 5);
    if (e >= nnz) return;
    int b = (int)(tid & 31);
    float v = vals[e];
    int s = src[e];
    int d = dst[e];
    atomicAdd(&yt[(size_t)d * NB + b], v * xt[(size_t)s * NB + b]);
}

// ---------------------------------------------------------------------------
// yt (M, B) -> out (B, M), + bias: 32x32 LDS tile transpose.
// ---------------------------------------------------------------------------
__global__ void finalize_kernel(const float* __restrict__ yt,
                                const float* __restrict__ bias,
                                float* __restrict__ out, int M) {
    __shared__ float tile[32][33];
    int m0 = blockIdx.x * 32;
    // read: lanes sweep batch (contiguous in yt), i sweeps m
    for (int i = threadIdx.y; i < 32; i += 8) {
        int m = m0 + i;
        tile[i][threadIdx.x] = (m < M) ? yt[(size_t)m * NB + threadIdx.x] : 0.f;
    }
    __syncthreads();
    // write: lanes sweep m (contiguous in out), i sweeps batch
    for (int i = threadIdx.y; i < 32; i += 8) {
        int m = m0 + threadIdx.x;
        if (m < M) out[(size_t)i * M + m] = tile[threadIdx.x][i] + bias[m];
    }
}

extern "C" void kernel_launch(void* const* d_in, const int* in_sizes, int n_in,
                              void* d_out, int out_size, void* d_ws, size_t ws_size,
                              hipStream_t stream) {
    const float* x       = (const float*)d_in[0];   // (B, N, 1) fp32
    const int*   indices = (const int*)  d_in[1];   // (2, NNZ) int32
    const float* vals    = (const float*)d_in[2];   // (NNZ,) fp32
    const float* bias    = (const float*)d_in[3];   // (M, 1) fp32

    float* out = (float*)d_out;                     // (B, M, 1) fp32

    int nnz = in_sizes[1] / 2;
    int N   = in_sizes[0] / NB;
    int M   = in_sizes[3];

    const int* src = indices;        // row 0
    const int* dst = indices + nnz;  // row 1

    // workspace: xt (N*B floats) | yt (M*B floats)  => 25.6 MB total
    float* xt = (float*)d_ws;
    float* yt = xt + (size_t)N * NB;

    // yt must be zeroed every call (ws is re-poisoned to 0xAA)
    hipMemsetAsync(yt, 0, (size_t)M * NB * sizeof(float), stream);

    transpose_x_kernel<<<(N + 31) / 32, dim3(32, 8), 0, stream>>>(x, xt, N);

    long long pairs = (long long)nnz * NB;
    int grid = (int)((pairs + 255) / 256);
    scatter_kernel<<<grid, 256, 0, stream>>>(src, dst, vals, xt, yt, nnz);

    finalize_kernel<<<(M + 31) / 32, dim3(32, 8), 0, stream>>>(yt, bias, out, M);
}